// Round 2
// baseline (621.055 us; speedup 1.0000x reference)
//
#include <hip/hip_runtime.h>

#define DD 128

// ---------- init: deg=1 (self loop), cnt=0, BN accumulators=0 ----------
__global__ void k_init(float* deg, int* cnt, float* colsum, float* colsumsq, int N) {
    int i = blockIdx.x * 256 + threadIdx.x;
    if (i < N) { deg[i] = 1.0f; cnt[i] = 0; }
    if (i < 128) { colsum[i] = 0.0f; colsumsq[i] = 0.0f; }
}

// ---------- pass1: out-degree (on sources) + in-count (on dests) ----------
__global__ void k_pass1(const int* __restrict__ ei, float* __restrict__ deg,
                        int* __restrict__ cnt, int E) {
    int e = blockIdx.x * 256 + threadIdx.x;
    if (e >= E) return;
    atomicAdd(&deg[ei[e]], 1.0f);      // row = source
    atomicAdd(&cnt[ei[E + e]], 1);     // col = dest
}

// ---------- dinv in place ----------
__global__ void k_dinv(float* deg, int N) {
    int i = blockIdx.x * 256 + threadIdx.x;
    if (i < N) deg[i] = rsqrtf(deg[i]);   // deg >= 1 always (self loop)
}

// ---------- 3-kernel exclusive scan of cnt -> rowptr (chunk = 512) ----------
__global__ void k_scan_a(const int* __restrict__ cnt, int* __restrict__ bsum, int N) {
    __shared__ int red[256];
    int t = threadIdx.x;
    int base = blockIdx.x * 512;
    int i0 = base + t, i1 = base + 256 + t;
    int s = ((i0 < N) ? cnt[i0] : 0) + ((i1 < N) ? cnt[i1] : 0);
    red[t] = s; __syncthreads();
    for (int off = 128; off > 0; off >>= 1) {
        if (t < off) red[t] += red[t + off];
        __syncthreads();
    }
    if (t == 0) bsum[blockIdx.x] = red[0];
}

__global__ void k_scan_b(const int* __restrict__ bsum, int* __restrict__ boff, int NB) {
    __shared__ int s[256];
    int t = threadIdx.x;
    int v0 = (t < NB) ? bsum[t] : 0;
    s[t] = v0; __syncthreads();
    for (int off = 1; off < 256; off <<= 1) {
        int v = (t >= off) ? s[t - off] : 0;
        __syncthreads();
        s[t] += v;
        __syncthreads();
    }
    if (t < NB) boff[t] = s[t] - v0;   // exclusive
}

__global__ void k_scan_c(const int* __restrict__ cnt, const int* __restrict__ boff,
                         int* __restrict__ rowptr, int* __restrict__ cursor, int N, int E) {
    __shared__ int s[256];
    int t = threadIdx.x;
    int base = blockIdx.x * 512;
    int i0 = base + 2 * t, i1 = base + 2 * t + 1;
    int a0 = (i0 < N) ? cnt[i0] : 0;
    int a1 = (i1 < N) ? cnt[i1] : 0;
    int tl = a0 + a1;
    s[t] = tl; __syncthreads();
    for (int off = 1; off < 256; off <<= 1) {
        int v = (t >= off) ? s[t - off] : 0;
        __syncthreads();
        s[t] += v;
        __syncthreads();
    }
    int excl = s[t] - tl + boff[blockIdx.x];
    if (i0 < N) { rowptr[i0] = excl;      cursor[i0] = 0; }
    if (i1 < N) { rowptr[i1] = excl + a0; cursor[i1] = 0; }
    if (blockIdx.x == 0 && t == 0) rowptr[N] = E;   // every non-self edge has one dest
}

// ---------- fill CSR: srcs + per-edge norm, bucketed by destination ----------
__global__ void k_fill(const int* __restrict__ ei, const float* __restrict__ ew,
                       const float* __restrict__ dinv, const int* __restrict__ rowptr,
                       int* __restrict__ cursor, int* __restrict__ srcs,
                       float* __restrict__ norms, int E) {
    int e = blockIdx.x * 256 + threadIdx.x;
    if (e >= E) return;
    int r = ei[e], c = ei[E + e];
    int pos = rowptr[c] + atomicAdd(&cursor[c], 1);
    srcs[pos] = r;
    norms[pos] = dinv[r] * dinv[c] * ew[e];
}

// ---------- GEMM: h = x @ W + b (all f32) ----------
// block = 256 (4 waves), 32 rows/block; lane owns a float2 column pair.
// LDS: x tile 16KB + W half-tile 32KB = 48KB.
__global__ __launch_bounds__(256) void k_gemm(const float* __restrict__ x,
                                              const float* __restrict__ W,
                                              const float* __restrict__ b,
                                              float* __restrict__ h, int N) {
    __shared__ float sx[32 * DD];      // 16KB  [row][k]
    __shared__ float2 sW[64 * 64];     // 32KB  [k_local][colpair]
    int t = threadIdx.x;
    int row0 = blockIdx.x * 32;
    // stage x tile: 32 rows x 128 f32 = 1024 float4
    const float4* xv = (const float4*)x;   // row stride = 32 float4
    float4* sxv = (float4*)sx;
    for (int i = t; i < 32 * 32; i += 256) {
        int r = row0 + (i >> 5);
        sxv[i] = (r < N) ? xv[(size_t)r * 32 + (i & 31)] : make_float4(0.f, 0.f, 0.f, 0.f);
    }
    int lane = t & 63, wave = t >> 6;
    float acc0[8], acc1[8];
#pragma unroll
    for (int r = 0; r < 8; ++r) { acc0[r] = 0.0f; acc1[r] = 0.0f; }
    const float* sxw = &sx[(wave * 8) * DD];
    for (int half = 0; half < 2; ++half) {
        __syncthreads();   // half 0: covers x-tile load; half 1: protects sW reuse
        const float2* Wp = (const float2*)(W + half * 64 * DD);
        for (int i = t; i < 64 * 64; i += 256) sW[i] = Wp[i];
        __syncthreads();
        int kbase = half * 64;
        for (int kk = 0; kk < 64; ++kk) {
            float2 wp = sW[kk * 64 + lane];
            int k = kbase + kk;
#pragma unroll
            for (int r = 0; r < 8; ++r) {
                float xr = sxw[r * DD + k];
                acc0[r] = fmaf(xr, wp.x, acc0[r]);
                acc1[r] = fmaf(xr, wp.y, acc1[r]);
            }
        }
    }
    float2 bb = ((const float2*)b)[lane];
    float2* hp = (float2*)h;
#pragma unroll
    for (int r = 0; r < 8; ++r) {
        int rr = row0 + wave * 8 + r;
        if (rr < N) hp[(size_t)rr * 64 + lane] = make_float2(acc0[r] + bb.x, acc1[r] + bb.y);
    }
}

// ---------- aggregate: out[n] = dinv[n]^2 * h[n] + sum_e norm[e] * h[src[e]] ----------
// one wave per node; lane owns a float2 column pair -> 512B coalesced gathers
__global__ __launch_bounds__(256) void k_aggregate(const float* __restrict__ h,
                                                   const int* __restrict__ rowptr,
                                                   const int* __restrict__ srcs,
                                                   const float* __restrict__ norms,
                                                   const float* __restrict__ dinv,
                                                   float* __restrict__ out, int N) {
    int wave = threadIdx.x >> 6, lane = threadIdx.x & 63;
    int n = blockIdx.x * 4 + wave;
    if (n >= N) return;
    const float2* hu = (const float2*)h;
    float dn = dinv[n];
    float sn = dn * dn;   // self-loop weight: dinv[n]*dinv[n]*1.0
    float2 p = hu[(size_t)n * 64 + lane];
    float a0 = sn * p.x, a1 = sn * p.y;
    int e = rowptr[n], e1 = rowptr[n + 1];
    for (; e < e1; ++e) {
        int s = srcs[e];
        float w = norms[e];
        float2 q = hu[(size_t)s * 64 + lane];
        a0 = fmaf(w, q.x, a0);
        a1 = fmaf(w, q.y, a1);
    }
    ((float2*)out)[(size_t)n * 64 + lane] = make_float2(a0, a1);
}

// ---------- BN stats: per-column sum & sumsq ----------
__global__ __launch_bounds__(256) void k_bn_stats(const float* __restrict__ out,
                                                  float* __restrict__ colsum,
                                                  float* __restrict__ colsumsq, int N) {
    __shared__ float ls[512], lq[512];
    int t = threadIdx.x, wave = t >> 6, lane = t & 63;
    const float2* ou = (const float2*)out;
    float s0 = 0, s1 = 0, q0 = 0, q1 = 0;
    for (int n = blockIdx.x * 4 + wave; n < N; n += gridDim.x * 4) {
        float2 p = ou[(size_t)n * 64 + lane];
        s0 += p.x; q0 += p.x * p.x;
        s1 += p.y; q1 += p.y * p.y;
    }
    ls[wave * 128 + lane * 2] = s0; ls[wave * 128 + lane * 2 + 1] = s1;
    lq[wave * 128 + lane * 2] = q0; lq[wave * 128 + lane * 2 + 1] = q1;
    __syncthreads();
    if (t < 128) {
        float S = ls[t] + ls[128 + t] + ls[256 + t] + ls[384 + t];
        float Q = lq[t] + lq[128 + t] + lq[256 + t] + lq[384 + t];
        atomicAdd(&colsum[t], S);
        atomicAdd(&colsumsq[t], Q);
    }
}

// ---------- BN finalize: per-column scale/shift ----------
__global__ void k_bn_final(const float* __restrict__ colsum, const float* __restrict__ colsumsq,
                           const float* __restrict__ gamma, const float* __restrict__ beta,
                           float* __restrict__ ss, int N) {
    int c = threadIdx.x;
    float invN = 1.0f / (float)N;
    float mean = colsum[c] * invN;
    float var = colsumsq[c] * invN - mean * mean;
    float inv = rsqrtf(var + 1e-5f);
    float sc = gamma[c] * inv;
    ss[c] = sc;
    ss[128 + c] = beta[c] - mean * sc;
}

// ---------- BN apply + ReLU, in place on d_out ----------
__global__ __launch_bounds__(256) void k_bn_apply(float* __restrict__ out,
                                                  const float* __restrict__ ss, int total64) {
    int i = blockIdx.x * 256 + threadIdx.x;
    if (i >= total64) return;
    int c0 = (i & 63) * 2;
    float2* ou = (float2*)out;
    float2 p = ou[i];
    float v0 = fmaxf(p.x * ss[c0] + ss[128 + c0], 0.0f);
    float v1 = fmaxf(p.y * ss[c0 + 1] + ss[128 + c0 + 1], 0.0f);
    ou[i] = make_float2(v0, v1);
}

extern "C" void kernel_launch(void* const* d_in, const int* in_sizes, int n_in,
                              void* d_out, int out_size, void* d_ws, size_t ws_size,
                              hipStream_t stream) {
    const float* x     = (const float*)d_in[0];
    const int* ei      = (const int*)d_in[1];
    const float* ew    = (const float*)d_in[2];
    const float* W     = (const float*)d_in[3];
    const float* b     = (const float*)d_in[4];
    const float* gamma = (const float*)d_in[5];
    const float* beta  = (const float*)d_in[6];
    float* out = (float*)d_out;

    int N = in_sizes[0] / DD;     // 100000
    int E = in_sizes[2];          // 1600000

    char* wsb = (char*)d_ws;
    size_t off = 0;
    auto alloc = [&](size_t bytes) -> char* {
        char* p = wsb + off;
        off = (off + bytes + 255) & ~(size_t)255;
        return p;
    };
    float* deg    = (float*)alloc((size_t)N * 4);        // -> dinv in place
    int* cnt      = (int*)alloc((size_t)N * 4);
    int* cursor   = (int*)alloc((size_t)N * 4);
    int* rowptr   = (int*)alloc((size_t)(N + 1) * 4);
    int* bsum     = (int*)alloc(256 * 4);
    int* boff     = (int*)alloc(256 * 4);
    int* srcs     = (int*)alloc((size_t)E * 4);
    float* norms  = (float*)alloc((size_t)E * 4);
    float* h      = (float*)alloc((size_t)N * DD * 4);
    float* colsum   = (float*)alloc(128 * 4);
    float* colsumsq = (float*)alloc(128 * 4);
    float* ss       = (float*)alloc(256 * 4);

    int NB = (N + 511) / 512;

    k_init<<<dim3((N + 255) / 256), dim3(256), 0, stream>>>(deg, cnt, colsum, colsumsq, N);
    k_pass1<<<dim3((E + 255) / 256), dim3(256), 0, stream>>>(ei, deg, cnt, E);
    k_dinv<<<dim3((N + 255) / 256), dim3(256), 0, stream>>>(deg, N);
    k_scan_a<<<dim3(NB), dim3(256), 0, stream>>>(cnt, bsum, N);
    k_scan_b<<<dim3(1), dim3(256), 0, stream>>>(bsum, boff, NB);
    k_scan_c<<<dim3(NB), dim3(256), 0, stream>>>(cnt, boff, rowptr, cursor, N, E);
    k_fill<<<dim3((E + 255) / 256), dim3(256), 0, stream>>>(ei, ew, deg, rowptr, cursor, srcs, norms, E);
    k_gemm<<<dim3((N + 31) / 32), dim3(256), 0, stream>>>(x, W, b, h, N);
    k_aggregate<<<dim3((N + 3) / 4), dim3(256), 0, stream>>>(h, rowptr, srcs, norms, deg, out, N);
    k_bn_stats<<<dim3(400), dim3(256), 0, stream>>>(out, colsum, colsumsq, N);
    k_bn_final<<<dim3(1), dim3(128), 0, stream>>>(colsum, colsumsq, gamma, beta, ss, N);
    k_bn_apply<<<dim3((N * 64 + 255) / 256), dim3(256), 0, stream>>>(out, ss, N * 64);
}

// Round 3
// 539.639 us; speedup vs baseline: 1.1509x; 1.1509x over previous
//
#include <hip/hip_runtime.h>

#define DD 128

// ---------- bf16 helpers (h is stored as packed bf16x2 in uint32) ----------
__device__ __forceinline__ unsigned short f2bf(float f) {
    unsigned int u; __builtin_memcpy(&u, &f, 4);
    unsigned int r = (u + 0x7FFFu + ((u >> 16) & 1u)) >> 16;
    return (unsigned short)r;
}
__device__ __forceinline__ unsigned int pack_bf(float a, float b) {
    return (unsigned int)f2bf(a) | ((unsigned int)f2bf(b) << 16);
}
__device__ __forceinline__ float lo_bf(unsigned int p) {
    unsigned int u = (p & 0xFFFFu) << 16; float f; __builtin_memcpy(&f, &u, 4); return f;
}
__device__ __forceinline__ float hi_bf(unsigned int p) {
    unsigned int u = p & 0xFFFF0000u; float f; __builtin_memcpy(&f, &u, 4); return f;
}
__device__ __forceinline__ float i2f(int v) { float f; __builtin_memcpy(&f, &v, 4); return f; }
__device__ __forceinline__ int f2i(float v) { int i; __builtin_memcpy(&i, &v, 4); return i; }

// ---------- init: deg=1 (self loop), cnt=0, BN accumulators=0 ----------
__global__ void k_init(float* deg, int* cnt, float* colsum, float* colsumsq, int N) {
    int i = blockIdx.x * 256 + threadIdx.x;
    if (i < N) { deg[i] = 1.0f; cnt[i] = 0; }
    if (i < 128) { colsum[i] = 0.0f; colsumsq[i] = 0.0f; }
}

// ---------- pass1: out-degree (on sources) + in-count (on dests) ----------
__global__ void k_pass1(const int* __restrict__ ei, float* __restrict__ deg,
                        int* __restrict__ cnt, int E) {
    int e = blockIdx.x * 256 + threadIdx.x;
    if (e >= E) return;
    atomicAdd(&deg[ei[e]], 1.0f);      // row = source
    atomicAdd(&cnt[ei[E + e]], 1);     // col = dest
}

// ---------- scan step a (chunk=512 block sums) + fused dinv ----------
__global__ void k_scan_a(const int* __restrict__ cnt, int* __restrict__ bsum,
                         float* __restrict__ deg, int N) {
    __shared__ int red[256];
    int t = threadIdx.x;
    int base = blockIdx.x * 512;
    int i0 = base + t, i1 = base + 256 + t;
    int s = ((i0 < N) ? cnt[i0] : 0) + ((i1 < N) ? cnt[i1] : 0);
    // fused dinv (deg >= 1 always because of the self loop)
    if (i0 < N) deg[i0] = rsqrtf(deg[i0]);
    if (i1 < N) deg[i1] = rsqrtf(deg[i1]);
    red[t] = s; __syncthreads();
    for (int off = 128; off > 0; off >>= 1) {
        if (t < off) red[t] += red[t + off];
        __syncthreads();
    }
    if (t == 0) bsum[blockIdx.x] = red[0];
}

__global__ void k_scan_b(const int* __restrict__ bsum, int* __restrict__ boff, int NB) {
    __shared__ int s[256];
    int t = threadIdx.x;
    int v0 = (t < NB) ? bsum[t] : 0;
    s[t] = v0; __syncthreads();
    for (int off = 1; off < 256; off <<= 1) {
        int v = (t >= off) ? s[t - off] : 0;
        __syncthreads();
        s[t] += v;
        __syncthreads();
    }
    if (t < NB) boff[t] = s[t] - v0;   // exclusive
}

__global__ void k_scan_c(const int* __restrict__ cnt, const int* __restrict__ boff,
                         int* __restrict__ rowptr, int* __restrict__ cursor, int N, int E) {
    __shared__ int s[256];
    int t = threadIdx.x;
    int base = blockIdx.x * 512;
    int i0 = base + 2 * t, i1 = base + 2 * t + 1;
    int a0 = (i0 < N) ? cnt[i0] : 0;
    int a1 = (i1 < N) ? cnt[i1] : 0;
    int tl = a0 + a1;
    s[t] = tl; __syncthreads();
    for (int off = 1; off < 256; off <<= 1) {
        int v = (t >= off) ? s[t - off] : 0;
        __syncthreads();
        s[t] += v;
        __syncthreads();
    }
    int excl = s[t] - tl + boff[blockIdx.x];
    if (i0 < N) { rowptr[i0] = excl;      cursor[i0] = 0; }
    if (i1 < N) { rowptr[i1] = excl + a0; cursor[i1] = 0; }
    if (blockIdx.x == 0 && t == 0) rowptr[N] = E;
}

// ---------- fill CSR: packed (src, norm) records bucketed by destination ----------
__global__ void k_fill(const int* __restrict__ ei, const float* __restrict__ ew,
                       const float* __restrict__ dinv, const int* __restrict__ rowptr,
                       int* __restrict__ cursor, int2* __restrict__ epk, int E) {
    int e = blockIdx.x * 256 + threadIdx.x;
    if (e >= E) return;
    int r = ei[e], c = ei[E + e];
    int pos = rowptr[c] + atomicAdd(&cursor[c], 1);
    int2 v;
    v.x = r;
    v.y = f2i(dinv[r] * dinv[c] * ew[e]);
    epk[pos] = v;
}

// ---------- GEMM: h = x @ W + b (f32 in, packed bf16x2 out) ----------
// block = 256 (4 waves), 32 rows/block; lane owns a column pair.
// LDS: x tile 16KB + W half-tile 32KB = 48KB.
__global__ __launch_bounds__(256) void k_gemm(const float* __restrict__ x,
                                              const float* __restrict__ W,
                                              const float* __restrict__ b,
                                              unsigned int* __restrict__ h, int N) {
    __shared__ float sx[32 * DD];      // 16KB  [row][k]
    __shared__ float2 sW[64 * 64];     // 32KB  [k_local][colpair]
    int t = threadIdx.x;
    int row0 = blockIdx.x * 32;
    const float4* xv = (const float4*)x;   // row stride = 32 float4
    float4* sxv = (float4*)sx;
    for (int i = t; i < 32 * 32; i += 256) {
        int r = row0 + (i >> 5);
        sxv[i] = (r < N) ? xv[(size_t)r * 32 + (i & 31)] : make_float4(0.f, 0.f, 0.f, 0.f);
    }
    int lane = t & 63, wave = t >> 6;
    float acc0[8], acc1[8];
#pragma unroll
    for (int r = 0; r < 8; ++r) { acc0[r] = 0.0f; acc1[r] = 0.0f; }
    const float* sxw = &sx[(wave * 8) * DD];
    for (int half = 0; half < 2; ++half) {
        __syncthreads();
        const float2* Wp = (const float2*)(W + half * 64 * DD);
        for (int i = t; i < 64 * 64; i += 256) sW[i] = Wp[i];
        __syncthreads();
        int kbase = half * 64;
        for (int kk = 0; kk < 64; ++kk) {
            float2 wp = sW[kk * 64 + lane];
            int k = kbase + kk;
#pragma unroll
            for (int r = 0; r < 8; ++r) {
                float xr = sxw[r * DD + k];
                acc0[r] = fmaf(xr, wp.x, acc0[r]);
                acc1[r] = fmaf(xr, wp.y, acc1[r]);
            }
        }
    }
    float2 bb = ((const float2*)b)[lane];
#pragma unroll
    for (int r = 0; r < 8; ++r) {
        int rr = row0 + wave * 8 + r;
        if (rr < N) h[(size_t)rr * 64 + lane] = pack_bf(acc0[r] + bb.x, acc1[r] + bb.y);
    }
}

// ---------- aggregate: out[n] = dinv[n]^2 * h[n] + sum_e norm[e] * h[src[e]] ----------
// one wave per node; lane owns a bf16x2 column pair (256B coalesced gathers);
// 4-deep unroll for memory-level parallelism.
__global__ __launch_bounds__(256) void k_aggregate(const unsigned int* __restrict__ h,
                                                   const int* __restrict__ rowptr,
                                                   const int2* __restrict__ epk,
                                                   const float* __restrict__ dinv,
                                                   float* __restrict__ out, int N) {
    int wave = threadIdx.x >> 6, lane = threadIdx.x & 63;
    int n = blockIdx.x * 4 + wave;
    if (n >= N) return;
    float dn = dinv[n];
    float sn = dn * dn;   // self-loop weight
    unsigned int p = h[(size_t)n * 64 + lane];
    float a0 = sn * lo_bf(p), a1 = sn * hi_bf(p);
    int e = rowptr[n], e1 = rowptr[n + 1];
    for (; e + 4 <= e1; e += 4) {
        int2 d0 = epk[e], d1 = epk[e + 1], d2 = epk[e + 2], d3 = epk[e + 3];
        unsigned int q0 = h[(size_t)d0.x * 64 + lane];
        unsigned int q1 = h[(size_t)d1.x * 64 + lane];
        unsigned int q2 = h[(size_t)d2.x * 64 + lane];
        unsigned int q3 = h[(size_t)d3.x * 64 + lane];
        float w0 = i2f(d0.y), w1 = i2f(d1.y), w2 = i2f(d2.y), w3 = i2f(d3.y);
        a0 = fmaf(w0, lo_bf(q0), a0); a1 = fmaf(w0, hi_bf(q0), a1);
        a0 = fmaf(w1, lo_bf(q1), a0); a1 = fmaf(w1, hi_bf(q1), a1);
        a0 = fmaf(w2, lo_bf(q2), a0); a1 = fmaf(w2, hi_bf(q2), a1);
        a0 = fmaf(w3, lo_bf(q3), a0); a1 = fmaf(w3, hi_bf(q3), a1);
    }
    for (; e < e1; ++e) {
        int2 d = epk[e];
        unsigned int q = h[(size_t)d.x * 64 + lane];
        float w = i2f(d.y);
        a0 = fmaf(w, lo_bf(q), a0);
        a1 = fmaf(w, hi_bf(q), a1);
    }
    ((float2*)out)[(size_t)n * 64 + lane] = make_float2(a0, a1);
}

// ---------- BN stats: per-column sum & sumsq ----------
__global__ __launch_bounds__(256) void k_bn_stats(const float* __restrict__ out,
                                                  float* __restrict__ colsum,
                                                  float* __restrict__ colsumsq, int N) {
    __shared__ float ls[512], lq[512];
    int t = threadIdx.x, wave = t >> 6, lane = t & 63;
    const float2* ou = (const float2*)out;
    float s0 = 0, s1 = 0, q0 = 0, q1 = 0;
    for (int n = blockIdx.x * 4 + wave; n < N; n += gridDim.x * 4) {
        float2 p = ou[(size_t)n * 64 + lane];
        s0 += p.x; q0 += p.x * p.x;
        s1 += p.y; q1 += p.y * p.y;
    }
    ls[wave * 128 + lane * 2] = s0; ls[wave * 128 + lane * 2 + 1] = s1;
    lq[wave * 128 + lane * 2] = q0; lq[wave * 128 + lane * 2 + 1] = q1;
    __syncthreads();
    if (t < 128) {
        float S = ls[t] + ls[128 + t] + ls[256 + t] + ls[384 + t];
        float Q = lq[t] + lq[128 + t] + lq[256 + t] + lq[384 + t];
        atomicAdd(&colsum[t], S);
        atomicAdd(&colsumsq[t], Q);
    }
}

// ---------- BN finalize: per-column scale/shift ----------
__global__ void k_bn_final(const float* __restrict__ colsum, const float* __restrict__ colsumsq,
                           const float* __restrict__ gamma, const float* __restrict__ beta,
                           float* __restrict__ ss, int N) {
    int c = threadIdx.x;
    float invN = 1.0f / (float)N;
    float mean = colsum[c] * invN;
    float var = colsumsq[c] * invN - mean * mean;
    float inv = rsqrtf(var + 1e-5f);
    float sc = gamma[c] * inv;
    ss[c] = sc;
    ss[128 + c] = beta[c] - mean * sc;
}

// ---------- BN apply + ReLU, in place on d_out ----------
__global__ __launch_bounds__(256) void k_bn_apply(float* __restrict__ out,
                                                  const float* __restrict__ ss, int total64) {
    int i = blockIdx.x * 256 + threadIdx.x;
    if (i >= total64) return;
    int c0 = (i & 63) * 2;
    float2* ou = (float2*)out;
    float2 p = ou[i];
    float v0 = fmaxf(p.x * ss[c0] + ss[128 + c0], 0.0f);
    float v1 = fmaxf(p.y * ss[c0 + 1] + ss[128 + c0 + 1], 0.0f);
    ou[i] = make_float2(v0, v1);
}

extern "C" void kernel_launch(void* const* d_in, const int* in_sizes, int n_in,
                              void* d_out, int out_size, void* d_ws, size_t ws_size,
                              hipStream_t stream) {
    const float* x     = (const float*)d_in[0];
    const int* ei      = (const int*)d_in[1];
    const float* ew    = (const float*)d_in[2];
    const float* W     = (const float*)d_in[3];
    const float* b     = (const float*)d_in[4];
    const float* gamma = (const float*)d_in[5];
    const float* beta  = (const float*)d_in[6];
    float* out = (float*)d_out;

    int N = in_sizes[0] / DD;     // 100000
    int E = in_sizes[2];          // 1600000

    char* wsb = (char*)d_ws;
    size_t off = 0;
    auto alloc = [&](size_t bytes) -> char* {
        char* p = wsb + off;
        off = (off + bytes + 255) & ~(size_t)255;
        return p;
    };
    float* deg    = (float*)alloc((size_t)N * 4);        // -> dinv in place
    int* cnt      = (int*)alloc((size_t)N * 4);
    int* cursor   = (int*)alloc((size_t)N * 4);
    int* rowptr   = (int*)alloc((size_t)(N + 1) * 4);
    int* bsum     = (int*)alloc(256 * 4);
    int* boff     = (int*)alloc(256 * 4);
    int2* epk     = (int2*)alloc((size_t)E * 8);         // packed (src, norm)
    unsigned int* h = (unsigned int*)alloc((size_t)N * 64 * 4);  // bf16x2 packed
    float* colsum   = (float*)alloc(128 * 4);
    float* colsumsq = (float*)alloc(128 * 4);
    float* ss       = (float*)alloc(256 * 4);

    int NB = (N + 511) / 512;

    k_init<<<dim3((N + 255) / 256), dim3(256), 0, stream>>>(deg, cnt, colsum, colsumsq, N);
    k_pass1<<<dim3((E + 255) / 256), dim3(256), 0, stream>>>(ei, deg, cnt, E);
    k_scan_a<<<dim3(NB), dim3(256), 0, stream>>>(cnt, bsum, deg, N);
    k_scan_b<<<dim3(1), dim3(256), 0, stream>>>(bsum, boff, NB);
    k_scan_c<<<dim3(NB), dim3(256), 0, stream>>>(cnt, boff, rowptr, cursor, N, E);
    k_fill<<<dim3((E + 255) / 256), dim3(256), 0, stream>>>(ei, ew, deg, rowptr, cursor, epk, E);
    k_gemm<<<dim3((N + 31) / 32), dim3(256), 0, stream>>>(x, W, b, h, N);
    k_aggregate<<<dim3((N + 3) / 4), dim3(256), 0, stream>>>(h, rowptr, epk, deg, out, N);
    k_bn_stats<<<dim3(400), dim3(256), 0, stream>>>(out, colsum, colsumsq, N);
    k_bn_final<<<dim3(1), dim3(128), 0, stream>>>(colsum, colsumsq, gamma, beta, ss, N);
    k_bn_apply<<<dim3((N * 64 + 255) / 256), dim3(256), 0, stream>>>(out, ss, N * 64);
}

// Round 4
// 379.991 us; speedup vs baseline: 1.6344x; 1.4201x over previous
//
#include <hip/hip_runtime.h>

#define DD 128

typedef __attribute__((ext_vector_type(8))) short short8;
typedef __attribute__((ext_vector_type(4))) float f32x4;

// ---------- bf16 helpers ----------
__device__ __forceinline__ unsigned short f2bf(float f) {
    unsigned int u; __builtin_memcpy(&u, &f, 4);
    unsigned int r = (u + 0x7FFFu + ((u >> 16) & 1u)) >> 16;
    return (unsigned short)r;
}
__device__ __forceinline__ float lo_bf(unsigned int p) {
    unsigned int u = (p & 0xFFFFu) << 16; float f; __builtin_memcpy(&f, &u, 4); return f;
}
__device__ __forceinline__ float hi_bf(unsigned int p) {
    unsigned int u = p & 0xFFFF0000u; float f; __builtin_memcpy(&f, &u, 4); return f;
}
__device__ __forceinline__ float i2f(int v) { float f; __builtin_memcpy(&f, &v, 4); return f; }
__device__ __forceinline__ int f2i(float v) { int i; __builtin_memcpy(&i, &v, 4); return i; }

// ---------- init: deg=1 (self loop), cnt=0, replicated BN accumulators=0 ----------
__global__ void k_init(int* deg, int* cnt, float* colsumR, float* colsumsqR, int N) {
    int i = blockIdx.x * 256 + threadIdx.x;
    if (i < N) { deg[i] = 1; cnt[i] = 0; }
    if (i < 1024) { colsumR[i] = 0.0f; colsumsqR[i] = 0.0f; }
}

// ---------- W prep: swizzle W (f32 [k][n]) into B-fragment order, bf16 ----------
// lane l of tile (tt,s) holds B[k = s*32 + (l>>4)*8 + j][n = tt*16 + (l&15)], j=0..7
__global__ void k_wprep(const float* __restrict__ W, unsigned short* __restrict__ Wfrag) {
    int i = blockIdx.x * 256 + threadIdx.x;   // 0..16383
    int k = i >> 7, n = i & 127;
    int tt = n >> 4, s = k >> 5, l = (((k >> 3) & 3) << 4) | (n & 15), j = k & 7;
    Wfrag[((tt * 4 + s) * 64 + l) * 8 + j] = f2bf(W[k * DD + n]);
}

// ---------- fused: histogram (even blocks) + MFMA GEMM (odd blocks) ----------
// Histogram waves stall on memory-side atomic drain (issue slots idle);
// MFMA waves co-scheduled on the same CUs hide the GEMM entirely.
__global__ __launch_bounds__(256) void k_fused(
    const int* __restrict__ ei, int* __restrict__ deg, int* __restrict__ cnt,
    int* __restrict__ posb, int E,
    const float* __restrict__ x, const unsigned short* __restrict__ Wfrag,
    const float* __restrict__ b, unsigned short* __restrict__ h, int N)
{
    int t = threadIdx.x;
    if ((blockIdx.x & 1) == 0) {
        // ---- histogram: 4 edges/thread; cnt atomic returns within-bucket pos ----
        int base = (blockIdx.x >> 1) * 1024 + t;
#pragma unroll
        for (int j = 0; j < 4; ++j) {
            int e = base + j * 256;
            if (e < E) {
                int r = ei[e], c = ei[E + e];
                posb[e] = atomicAdd(&cnt[c], 1);
                atomicAdd(&deg[r], 1);
            }
        }
        return;
    }
    // ---- GEMM: 64 rows/block, wave strip = 16 rows, full 128-col width ----
    int gb = blockIdx.x >> 1;
    int lane = t & 63, wave = t >> 6;
    int row0 = gb * 64 + wave * 16;
    int mrow = row0 + (lane & 15);    // A-operand row
    int kgrp = lane >> 4;             // A-operand k-group
    f32x4 acc[8];
#pragma unroll
    for (int i = 0; i < 8; ++i) acc[i] = (f32x4){0.f, 0.f, 0.f, 0.f};
    const short8* Wf = (const short8*)Wfrag;
#pragma unroll
    for (int s = 0; s < 4; ++s) {
        float xv[8];
        if (mrow < N) {
            const float4* xp = (const float4*)(x + (size_t)mrow * DD + s * 32 + kgrp * 8);
            float4 xa = xp[0], xb = xp[1];
            xv[0] = xa.x; xv[1] = xa.y; xv[2] = xa.z; xv[3] = xa.w;
            xv[4] = xb.x; xv[5] = xb.y; xv[6] = xb.z; xv[7] = xb.w;
        } else {
#pragma unroll
            for (int j = 0; j < 8; ++j) xv[j] = 0.f;
        }
        short8 af;
#pragma unroll
        for (int j = 0; j < 8; ++j) af[j] = (short)f2bf(xv[j]);
#pragma unroll
        for (int tt = 0; tt < 8; ++tt) {
            short8 bf = Wf[(tt * 4 + s) * 64 + lane];
            acc[tt] = __builtin_amdgcn_mfma_f32_16x16x32_bf16(af, bf, acc[tt], 0, 0, 0);
        }
    }
    // epilogue: D row = (lane>>4)*4 + reg, col = lane&15 (within 16-col tile)
    int drow = row0 + (lane >> 4) * 4;
    int coll = lane & 15;
#pragma unroll
    for (int tt = 0; tt < 8; ++tt) {
        int col = tt * 16 + coll;
        float bias = b[col];
#pragma unroll
        for (int rr = 0; rr < 4; ++rr) {
            int row = drow + rr;
            if (row < N) h[(size_t)row * DD + col] = f2bf(acc[tt][rr] + bias);
        }
    }
}

// ---------- scan a: chunk-512 block sums + fused dinv (int deg -> float rsqrt) ----------
__global__ void k_scan_a(const int* __restrict__ cnt, int* __restrict__ bsum,
                         const int* __restrict__ degi, float* __restrict__ dinv, int N) {
    __shared__ int red[256];
    int t = threadIdx.x;
    int base = blockIdx.x * 512;
    int i0 = base + t, i1 = base + 256 + t;
    int s = ((i0 < N) ? cnt[i0] : 0) + ((i1 < N) ? cnt[i1] : 0);
    if (i0 < N) dinv[i0] = rsqrtf((float)degi[i0]);
    if (i1 < N) dinv[i1] = rsqrtf((float)degi[i1]);
    red[t] = s; __syncthreads();
    for (int off = 128; off > 0; off >>= 1) {
        if (t < off) red[t] += red[t + off];
        __syncthreads();
    }
    if (t == 0) bsum[blockIdx.x] = red[0];
}

__global__ void k_scan_b(const int* __restrict__ bsum, int* __restrict__ boff, int NB) {
    __shared__ int s[256];
    int t = threadIdx.x;
    int v0 = (t < NB) ? bsum[t] : 0;
    s[t] = v0; __syncthreads();
    for (int off = 1; off < 256; off <<= 1) {
        int v = (t >= off) ? s[t - off] : 0;
        __syncthreads();
        s[t] += v;
        __syncthreads();
    }
    if (t < NB) boff[t] = s[t] - v0;   // exclusive
}

__global__ void k_scan_c(const int* __restrict__ cnt, const int* __restrict__ boff,
                         int* __restrict__ rowptr, int N, int E) {
    __shared__ int s[256];
    int t = threadIdx.x;
    int base = blockIdx.x * 512;
    int i0 = base + 2 * t, i1 = base + 2 * t + 1;
    int a0 = (i0 < N) ? cnt[i0] : 0;
    int a1 = (i1 < N) ? cnt[i1] : 0;
    int tl = a0 + a1;
    s[t] = tl; __syncthreads();
    for (int off = 1; off < 256; off <<= 1) {
        int v = (t >= off) ? s[t - off] : 0;
        __syncthreads();
        s[t] += v;
        __syncthreads();
    }
    int excl = s[t] - tl + boff[blockIdx.x];
    if (i0 < N) rowptr[i0] = excl;
    if (i1 < N) rowptr[i1] = excl + a0;
    if (blockIdx.x == 0 && t == 0) rowptr[N] = E;
}

// ---------- fill CSR (atomic-free): pos = rowptr[dest] + posb[e] ----------
__global__ void k_fill(const int* __restrict__ ei, const float* __restrict__ ew,
                       const float* __restrict__ dinv, const int* __restrict__ rowptr,
                       const int* __restrict__ posb, int2* __restrict__ epk, int E) {
    int e = blockIdx.x * 256 + threadIdx.x;
    if (e >= E) return;
    int r = ei[e], c = ei[E + e];
    int pos = rowptr[c] + posb[e];
    int2 v;
    v.x = r;
    v.y = f2i(dinv[r] * dinv[c] * ew[e]);
    epk[pos] = v;
}

// ---------- aggregate + fused BN stats ----------
// grid-stride over nodes, 1024 thr/block (16 waves); lane owns a fixed bf16x2
// col-pair -> running col sums live in registers across all its nodes.
__global__ __launch_bounds__(1024) void k_aggregate(
    const unsigned int* __restrict__ h, const int* __restrict__ rowptr,
    const int2* __restrict__ epk, const float* __restrict__ dinv,
    float* __restrict__ out, float* __restrict__ colsumR,
    float* __restrict__ colsumsqR, int N)
{
    __shared__ float ls[2048], lq[2048];
    int t = threadIdx.x, wave = t >> 6, lane = t & 63;
    int gw = blockIdx.x * 16 + wave;
    float s0 = 0, s1 = 0, q0 = 0, q1 = 0;
    for (int n = gw; n < N; n += 512 * 16) {
        float dn = dinv[n];
        float sn = dn * dn;   // self-loop weight
        unsigned int p = h[(size_t)n * 64 + lane];
        float a0 = sn * lo_bf(p), a1 = sn * hi_bf(p);
        int e = rowptr[n], e1 = rowptr[n + 1];
        for (; e + 4 <= e1; e += 4) {
            int2 d0 = epk[e], d1 = epk[e + 1], d2 = epk[e + 2], d3 = epk[e + 3];
            unsigned int q0_ = h[(size_t)d0.x * 64 + lane];
            unsigned int q1_ = h[(size_t)d1.x * 64 + lane];
            unsigned int q2_ = h[(size_t)d2.x * 64 + lane];
            unsigned int q3_ = h[(size_t)d3.x * 64 + lane];
            float w0 = i2f(d0.y), w1 = i2f(d1.y), w2 = i2f(d2.y), w3 = i2f(d3.y);
            a0 = fmaf(w0, lo_bf(q0_), a0); a1 = fmaf(w0, hi_bf(q0_), a1);
            a0 = fmaf(w1, lo_bf(q1_), a0); a1 = fmaf(w1, hi_bf(q1_), a1);
            a0 = fmaf(w2, lo_bf(q2_), a0); a1 = fmaf(w2, hi_bf(q2_), a1);
            a0 = fmaf(w3, lo_bf(q3_), a0); a1 = fmaf(w3, hi_bf(q3_), a1);
        }
        for (; e < e1; ++e) {
            int2 d = epk[e];
            unsigned int q = h[(size_t)d.x * 64 + lane];
            float w = i2f(d.y);
            a0 = fmaf(w, lo_bf(q), a0);
            a1 = fmaf(w, hi_bf(q), a1);
        }
        ((float2*)out)[(size_t)n * 64 + lane] = make_float2(a0, a1);
        s0 += a0; q0 += a0 * a0;
        s1 += a1; q1 += a1 * a1;
    }
    ls[wave * 128 + lane * 2] = s0; ls[wave * 128 + lane * 2 + 1] = s1;
    lq[wave * 128 + lane * 2] = q0; lq[wave * 128 + lane * 2 + 1] = q1;
    __syncthreads();
    if (t < 128) {
        float S = 0, Q = 0;
#pragma unroll
        for (int w = 0; w < 16; ++w) { S += ls[w * 128 + t]; Q += lq[w * 128 + t]; }
        int rep = (blockIdx.x & 7) * 128 + t;   // 8-way replication cuts contention
        atomicAdd(&colsumR[rep], S);
        atomicAdd(&colsumsqR[rep], Q);
    }
}

// ---------- BN finalize: sum replicas, compute per-column scale/shift ----------
__global__ void k_bn_final(const float* __restrict__ colsumR, const float* __restrict__ colsumsqR,
                           const float* __restrict__ gamma, const float* __restrict__ beta,
                           float* __restrict__ ss, int N) {
    int c = threadIdx.x;
    float S = 0, Q = 0;
#pragma unroll
    for (int r = 0; r < 8; ++r) { S += colsumR[r * 128 + c]; Q += colsumsqR[r * 128 + c]; }
    float invN = 1.0f / (float)N;
    float mean = S * invN;
    float var = Q * invN - mean * mean;
    float inv = rsqrtf(var + 1e-5f);
    float sc = gamma[c] * inv;
    ss[c] = sc;
    ss[128 + c] = beta[c] - mean * sc;
}

// ---------- BN apply + ReLU, in place on d_out ----------
__global__ __launch_bounds__(256) void k_bn_apply(float* __restrict__ out,
                                                  const float* __restrict__ ss, int total64) {
    int i = blockIdx.x * 256 + threadIdx.x;
    if (i >= total64) return;
    int c0 = (i & 63) * 2;
    float2* ou = (float2*)out;
    float2 p = ou[i];
    float v0 = fmaxf(p.x * ss[c0] + ss[128 + c0], 0.0f);
    float v1 = fmaxf(p.y * ss[c0 + 1] + ss[128 + c0 + 1], 0.0f);
    ou[i] = make_float2(v0, v1);
}

extern "C" void kernel_launch(void* const* d_in, const int* in_sizes, int n_in,
                              void* d_out, int out_size, void* d_ws, size_t ws_size,
                              hipStream_t stream) {
    const float* x     = (const float*)d_in[0];
    const int* ei      = (const int*)d_in[1];
    const float* ew    = (const float*)d_in[2];
    const float* W     = (const float*)d_in[3];
    const float* b     = (const float*)d_in[4];
    const float* gamma = (const float*)d_in[5];
    const float* beta  = (const float*)d_in[6];
    float* out = (float*)d_out;

    int N = in_sizes[0] / DD;     // 100000
    int E = in_sizes[2];          // 1600000

    char* wsb = (char*)d_ws;
    size_t off = 0;
    auto alloc = [&](size_t bytes) -> char* {
        char* p = wsb + off;
        off = (off + bytes + 255) & ~(size_t)255;
        return p;
    };
    int* deg      = (int*)alloc((size_t)N * 4);          // int counts -> float dinv in place
    float* dinv   = (float*)deg;
    int* cnt      = (int*)alloc((size_t)N * 4);
    int* posb     = (int*)alloc((size_t)E * 4);          // within-bucket positions
    int* rowptr   = (int*)alloc((size_t)(N + 1) * 4);
    int* bsum     = (int*)alloc(256 * 4);
    int* boff     = (int*)alloc(256 * 4);
    int2* epk     = (int2*)alloc((size_t)E * 8);         // packed (src, norm)
    unsigned short* h = (unsigned short*)alloc((size_t)N * DD * 2);  // bf16
    unsigned short* Wfrag = (unsigned short*)alloc(DD * DD * 2);     // B-frag swizzled
    float* colsumR   = (float*)alloc(1024 * 4);
    float* colsumsqR = (float*)alloc(1024 * 4);
    float* ss        = (float*)alloc(256 * 4);

    int NB = (N + 511) / 512;
    int GH = (E + 1023) / 1024;          // 1563 histogram blocks (4 edges/thread)
    // gemm blocks: ceil(N/64) = 1563 as well; interleave even/odd
    int GG = (N + 63) / 64;
    int GF = 2 * ((GH > GG) ? GH : GG);

    k_init<<<dim3((N + 255) / 256), dim3(256), 0, stream>>>(deg, cnt, colsumR, colsumsqR, N);
    k_wprep<<<dim3(64), dim3(256), 0, stream>>>(W, Wfrag);
    k_fused<<<dim3(GF), dim3(256), 0, stream>>>(ei, deg, cnt, posb, E, x, Wfrag, b, h, N);
    k_scan_a<<<dim3(NB), dim3(256), 0, stream>>>(cnt, bsum, deg, dinv, N);
    k_scan_b<<<dim3(1), dim3(256), 0, stream>>>(bsum, boff, NB);
    k_scan_c<<<dim3(NB), dim3(256), 0, stream>>>(cnt, boff, rowptr, N, E);
    k_fill<<<dim3((E + 255) / 256), dim3(256), 0, stream>>>(ei, ew, dinv, rowptr, posb, epk, E);
    k_aggregate<<<dim3(512), dim3(1024), 0, stream>>>((const unsigned int*)h, rowptr, epk, dinv,
                                                      out, colsumR, colsumsqR, N);
    k_bn_final<<<dim3(1), dim3(128), 0, stream>>>(colsumR, colsumsqR, gamma, beta, ss, N);
    k_bn_apply<<<dim3((N * 64 + 255) / 256), dim3(256), 0, stream>>>(out, ss, N * 64);
}